// Round 1
// baseline (2233.457 us; speedup 1.0000x reference)
//
#include <hip/hip_runtime.h>
#include <hip/hip_bf16.h>

// SINDy layer: out[65536,32] = Theta(z)[65536,6545] @ (Xi*Xi_mask)[6545,32]
// Strategy: fused bf16 MFMA GEMM. Theta generated in registers per lane with
// compile-time (i,j,k) indices (constexpr table + full K unroll); Xi_eff
// pre-packed to B-fragment layout in d_ws by a prep kernel.
// MFMA 32x32x16_bf16 layouts (per cdna_hip_programming.md §3, m74/m101/m120):
//   A[m][k]: m=lane&31, k=(lane>>5)*8+j   (j = element of short8)
//   B[k][n]: n=lane&31, k=(lane>>5)*8+j
//   C/D:     col=lane&31, row=(reg&3)+8*(reg>>2)+4*(lane>>5)

#define Z 32
#define NTERMS 6545           // 1 + 32 + 528 + 5984
#define NCHUNK 410            // ceil(6545/16) -> 6560 padded terms
#define NT_PAD (NCHUNK * 16)
#define ROWS 65536
#define WAVES (ROWS / 32)     // 2048 waves, one 32x32 tile each
#define WPB 4                 // waves per block (256 threads)
#define NBLK (WAVES / WPB)    // 512 blocks

typedef short short8 __attribute__((ext_vector_type(8)));
typedef float f32x16 __attribute__((ext_vector_type(16)));

// ---- compile-time term index table (index 32 == virtual z[32] = 1.0) ----
struct Tabs {
    short ti[NT_PAD];
    short tj[NT_PAD];
    short tk[NT_PAD];
};
constexpr Tabs make_tabs() {
    Tabs t{};
    int n = 0;
    // bias
    t.ti[n] = 32; t.tj[n] = 32; t.tk[n] = 32; ++n;
    // linear
    for (int a = 0; a < Z; ++a) { t.ti[n] = (short)a; t.tj[n] = 32; t.tk[n] = 32; ++n; }
    // pairs (np.triu_indices order: i<=j, row-major)
    for (int a = 0; a < Z; ++a)
        for (int b = a; b < Z; ++b) { t.ti[n] = (short)a; t.tj[n] = (short)b; t.tk[n] = 32; ++n; }
    // triples i<=j<=k lexicographic
    for (int a = 0; a < Z; ++a)
        for (int b = a; b < Z; ++b)
            for (int c = b; c < Z; ++c) { t.ti[n] = (short)a; t.tj[n] = (short)b; t.tk[n] = (short)c; ++n; }
    // padding: theta=1.0, Xi rows are zeroed by prep -> contributes 0
    for (; n < NT_PAD; ++n) { t.ti[n] = 32; t.tj[n] = 32; t.tk[n] = 32; }
    return t;
}
constexpr Tabs TAB = make_tabs();

// ---- prep: pack Xi_eff (bf16, RNE) into B-fragment order in ws ----
// layout: Bp[c*64 + lane] = uint4 holding 8 bf16: term = c*16 + (lane>>5)*8 + j,
//         col n = lane&31
__global__ void sindy_prep(const float* __restrict__ Xi,
                           const float* __restrict__ Xi_mask,
                           uint4* __restrict__ Bp) {
    int tid = blockIdx.x * blockDim.x + threadIdx.x;
    if (tid >= NCHUNK * 64) return;
    int c = tid >> 6, l = tid & 63;
    int n = l & 31, h = l >> 5;
    unsigned v[8];
#pragma unroll
    for (int j = 0; j < 8; ++j) {
        int t = c * 16 + h * 8 + j;
        float f = 0.0f;
        if (t < NTERMS) f = Xi[t * Z + n] * Xi_mask[t * Z + n];
        unsigned u = __builtin_bit_cast(unsigned, f);
        v[j] = (u + 0x7FFFu + ((u >> 16) & 1u)) >> 16;   // RNE to bf16
    }
    uint4 o;
    o.x = v[0] | (v[1] << 16);
    o.y = v[2] | (v[3] << 16);
    o.z = v[4] | (v[5] << 16);
    o.w = v[6] | (v[7] << 16);
    Bp[tid] = o;
}

// ---- main: one wave = one 32-row x 32-col output tile, full K loop ----
__global__ __launch_bounds__(256, 2) void sindy_mfma(const float* __restrict__ z,
                                                     const uint4* __restrict__ Bp,
                                                     float* __restrict__ out) {
    const int lane = threadIdx.x & 63;
    const int wave = blockIdx.x * WPB + (threadIdx.x >> 6);
    const int m = lane & 31;       // my output row within tile (A's M index)
    const int half = lane >> 5;    // my k-half
    const long R = (long)wave * 32;

    // my row's z into registers; zr[32] = 1.0 sentinel
    float zr[33];
    const float4* z4 = (const float4*)(z + (R + m) * Z);
#pragma unroll
    for (int q = 0; q < 8; ++q) {
        float4 v = z4[q];
        zr[4 * q + 0] = v.x; zr[4 * q + 1] = v.y;
        zr[4 * q + 2] = v.z; zr[4 * q + 3] = v.w;
    }
    zr[32] = 1.0f;

    f32x16 acc = {};
    const uint4* bp = Bp + lane;

#pragma unroll
    for (int c = 0; c < NCHUNK; ++c) {
        // all 16 thetas of this chunk (compile-time indices -> pure v_mul;
        // shared zr[i]*zr[j] pair-products CSE'd by the compiler)
        float th[16];
#pragma unroll
        for (int u = 0; u < 16; ++u) {
            const int t = c * 16 + u;
            float v = zr[TAB.ti[t]];
            if (TAB.tj[t] != 32) v *= zr[TAB.tj[t]];
            if (TAB.tk[t] != 32) v *= zr[TAB.tk[t]];
            th[u] = v;
        }
        // select my half's 8, round-to-bf16 (half-up), pack into short8
        union { unsigned u32[4]; short8 s; } a;
#pragma unroll
        for (int r = 0; r < 4; ++r) {
            float s0 = half ? th[8 + 2 * r] : th[2 * r];
            float s1 = half ? th[8 + 2 * r + 1] : th[2 * r + 1];
            unsigned b0 = __builtin_bit_cast(unsigned, s0) + 0x8000u;
            unsigned b1 = __builtin_bit_cast(unsigned, s1) + 0x8000u;
            a.u32[r] = (b0 >> 16) | (b1 & 0xFFFF0000u);   // lo16=k even, hi16=k odd
        }
        union { uint4 q; short8 s; } b;
        b.q = bp[c * 64];
        acc = __builtin_amdgcn_mfma_f32_32x32x16_bf16(a.s, b.s, acc, 0, 0, 0);
    }

    // epilogue: C/D layout -> coalesced stores
    float* orow = out + R * Z;
#pragma unroll
    for (int r = 0; r < 16; ++r) {
        int row = (r & 3) + 8 * (r >> 2) + 4 * half;
        orow[row * Z + m] = acc[r];
    }
}

extern "C" void kernel_launch(void* const* d_in, const int* in_sizes, int n_in,
                              void* d_out, int out_size, void* d_ws, size_t ws_size,
                              hipStream_t stream) {
    const float* z       = (const float*)d_in[0];
    const float* Xi      = (const float*)d_in[1];
    const float* Xi_mask = (const float*)d_in[2];
    // d_in[3]=z_mean, d_in[4]=z_std: unused by the reference
    float* out = (float*)d_out;
    uint4* Bp  = (uint4*)d_ws;   // NCHUNK*64*16 = 419,840 bytes

    int prep_threads = NCHUNK * 64;
    sindy_prep<<<(prep_threads + 255) / 256, 256, 0, stream>>>(Xi, Xi_mask, Bp);
    sindy_mfma<<<NBLK, 256, 0, stream>>>(z, Bp, out);
}

// Round 2
// 181.271 us; speedup vs baseline: 12.3211x; 12.3211x over previous
//
#include <hip/hip_runtime.h>

// SINDy: out[65536,32] = Theta(z)[65536,6545] @ (Xi*Xi_mask)[6545,32]
// Round-2 structure: augmented z~=(z,1); every term = z~i*z~j*z~k (i<=j<=k over 33).
// Term -> (pair (i,j) wave-uniform from table, k in static quarter q).
// 4 static-q segments, rolled loops: A-frag theta = p * zr[8q+jj] with jj static
// -> no dynamic register indexing, no mega-unroll. p via 2 ds_read of the lane's
// z-row staged in LDS (stride 33 -> bank (m+i)%32, conflict-free).
// MFMA 32x32x16_bf16 layouts (verified passing in round 1):
//   A[m][k]: m=lane&31, k=(lane>>5)*8+jj
//   B[k][n]: n=lane&31, k=(lane>>5)*8+jj
//   C/D:     col=lane&31, row=(reg&3)+8*(reg>>2)+4*(lane>>5)

#define Z 32
#define ROWS 65536
#define WPB 4
#define NBLK (ROWS / 32 / WPB)   // 512 blocks x 4 waves, one 32x32 tile per wave

#define NCHUNK 544               // 35 + 81 + 159 + 269
#define NGRAN (NCHUNK * 2)

typedef short short8 __attribute__((ext_vector_type(8)));
typedef float f32x16 __attribute__((ext_vector_type(16)));

struct Sched {
    int nq[4];                 // chunks per quarter-segment
    unsigned meta[NCHUNK];     // i0 | j0<<8 | i1<<16 | j1<<24  (granule pair per chunk)
    short gi[NGRAN], gj[NGRAN];
    char gtype[NGRAN];         // 0 triple, 1 pair-times-1, 2 linear, 3 pad
    char gq[NGRAN];            // quarter of granule
    int tidx[32][32];          // index of triple (a,b,b) within triples block
    int pidx[32];              // index of pair (i,i) within pairs block
};

constexpr Sched make_sched() {
    Sched s{};
    int g = 0;
    for (int q = 0; q < 4; ++q) {
        int g0 = g;
        // triple granules (a<=b): cover k in [8q,8q+8) for k>=b  -> need b>>3 <= q
        for (int b = 0; b < 32; ++b)
            if ((b >> 3) <= q)
                for (int a = 0; a <= b; ++a) {
                    s.gi[g] = (short)a; s.gj[g] = (short)b; s.gtype[g] = 0; s.gq[g] = (char)q; ++g;
                }
        // pair granules (b,32): theta = z_b * z_k, valid slots k<=b -> need b>>3 >= q
        for (int b = 0; b < 32; ++b)
            if ((b >> 3) >= q) {
                s.gi[g] = (short)b; s.gj[g] = 32; s.gtype[g] = 1; s.gq[g] = (char)q; ++g;
            }
        // linear granule (32,32): theta = z_k
        s.gi[g] = 32; s.gj[g] = 32; s.gtype[g] = 2; s.gq[g] = (char)q; ++g;
        // pad to even granule count (pairing two granules per 16-k chunk)
        if ((g - g0) & 1) { s.gi[g] = 32; s.gj[g] = 32; s.gtype[g] = 3; s.gq[g] = (char)q; ++g; }
        s.nq[q] = (g - g0) / 2;
    }
    for (int c = 0; c < NCHUNK; ++c)
        s.meta[c] = (unsigned)s.gi[2*c] | ((unsigned)s.gj[2*c] << 8)
                  | ((unsigned)s.gi[2*c+1] << 16) | ((unsigned)s.gj[2*c+1] << 24);
    int n = 0;
    for (int a = 0; a < 32; ++a)
        for (int b = a; b < 32; ++b) { s.tidx[a][b] = n; n += 32 - b; }
    for (int i = 0; i < 32; ++i) s.pidx[i] = i * 32 - i * (i - 1) / 2;
    return s;
}
constexpr Sched S = make_sched();
static_assert(S.nq[0] == 35 && S.nq[1] == 81 && S.nq[2] == 159 && S.nq[3] == 269, "chunk counts");
static_assert(S.tidx[31][31] == 5983, "triple indexing");

// ---- prep: pack Xi_eff (bf16 RNE) into granule-ordered B fragments in ws ----
// Bp[c*64 + lane]: n = lane&31, granule = lane>>5 within chunk c, slots k = 8q+jj
__global__ void sindy_prep(const float* __restrict__ Xi,
                           const float* __restrict__ Xi_mask,
                           uint4* __restrict__ Bp) {
    int tid = blockIdx.x * blockDim.x + threadIdx.x;
    if (tid >= NCHUNK * 64) return;
    int c = tid >> 6, l = tid & 63;
    int g = 2 * c + (l >> 5);
    int n = l & 31;
    int i = S.gi[g], j = S.gj[g], ty = S.gtype[g], q = S.gq[g];
    unsigned v[8];
#pragma unroll
    for (int jj = 0; jj < 8; ++jj) {
        int k = 8 * q + jj;
        int row = -1;
        if (ty == 0)      { if (k >= j) row = 561 + S.tidx[i][j] + (k - j); }   // triple (i,j,k)
        else if (ty == 1) { if (k <= i) row = 33 + S.pidx[k] + (i - k); }       // pair (k,i)
        else if (ty == 2) { row = 1 + k; }                                      // linear z_k
        float f = 0.0f;
        if (row >= 0) f = Xi[row * Z + n] * Xi_mask[row * Z + n];
        unsigned u = __builtin_bit_cast(unsigned, f);
        v[jj] = (u + 0x7FFFu + ((u >> 16) & 1u)) >> 16;   // RNE to bf16
    }
    uint4 o;
    o.x = v[0] | (v[1] << 16);
    o.y = v[2] | (v[3] << 16);
    o.z = v[4] | (v[5] << 16);
    o.w = v[6] | (v[7] << 16);
    Bp[tid] = o;
}

// ---- main: one wave per 32x32 output tile, 544-chunk K loop in 4 segments ----
__global__ __launch_bounds__(256, 2) void sindy_mfma(const float* __restrict__ z,
                                                     const float* __restrict__ Xi,
                                                     const float* __restrict__ Xi_mask,
                                                     const uint4* __restrict__ Bp,
                                                     float* __restrict__ out) {
    const int lane = threadIdx.x & 63;
    const int w = threadIdx.x >> 6;
    const int m = lane & 31;
    const int half = lane >> 5;
    const int wave = blockIdx.x * WPB + w;
    const long R = (long)wave * 32;

    __shared__ float zs[WPB][32][33];   // stride 33: bank (m+i)%32, conflict-free

    // my row's z in registers (static-indexed only)
    float zr[32];
    const float4* z4 = (const float4*)(z + (R + m) * Z);
#pragma unroll
    for (int t = 0; t < 8; ++t) {
        float4 v = z4[t];
        zr[4*t+0] = v.x; zr[4*t+1] = v.y; zr[4*t+2] = v.z; zr[4*t+3] = v.w;
    }
    // stage row into LDS (dynamic-indexable), z~[32] = 1.0 sentinel
#pragma unroll
    for (int t = 0; t < 16; ++t) zs[w][m][half * 16 + t] = zr[half * 16 + t];
    if (half == 0) zs[w][m][32] = 1.0f;
    __syncthreads();

    const float bias = Xi[m] * Xi_mask[m];   // library row 0 (ones column), col n = m
    f32x16 acc = {};
    const float* zrow = &zs[w][m][0];
    const uint4* bp = Bp + lane;
    int c = 0;

#define SEG(Q)                                                                          \
    for (int t = 0; t < S.nq[Q]; ++t, ++c) {                                            \
        unsigned mw = S.meta[c];               /* uniform -> s_load */                  \
        unsigned ij = half ? (mw >> 16) : (mw & 0xFFFFu);                               \
        float p = zrow[ij & 0xFFu] * zrow[(ij >> 8) & 0xFFu];                           \
        union { unsigned u32[4]; short8 s; } a;                                         \
        _Pragma("unroll")                                                               \
        for (int r = 0; r < 4; ++r) {                                                   \
            unsigned b0 = __builtin_bit_cast(unsigned, p * zr[8 * Q + 2 * r])     + 0x8000u; \
            unsigned b1 = __builtin_bit_cast(unsigned, p * zr[8 * Q + 2 * r + 1]) + 0x8000u; \
            a.u32[r] = __builtin_amdgcn_perm(b1, b0, 0x07060302u);  /* hi16(b0)|hi16(b1)<<16 */ \
        }                                                                               \
        union { uint4 v; short8 s; } b;                                                 \
        b.v = bp[(size_t)c * 64];                                                       \
        acc = __builtin_amdgcn_mfma_f32_32x32x16_bf16(a.s, b.s, acc, 0, 0, 0);          \
    }

    SEG(0) SEG(1) SEG(2) SEG(3)
#undef SEG

#pragma unroll
    for (int r = 0; r < 16; ++r) acc[r] += bias;

    // C/D layout -> stores (verified in round 1)
    float* orow = out + R * Z;
#pragma unroll
    for (int r = 0; r < 16; ++r) {
        int row = (r & 3) + 8 * (r >> 2) + 4 * half;
        orow[row * Z + m] = acc[r];
    }
}

extern "C" void kernel_launch(void* const* d_in, const int* in_sizes, int n_in,
                              void* d_out, int out_size, void* d_ws, size_t ws_size,
                              hipStream_t stream) {
    const float* z       = (const float*)d_in[0];
    const float* Xi      = (const float*)d_in[1];
    const float* Xi_mask = (const float*)d_in[2];
    // d_in[3]=z_mean, d_in[4]=z_std: unused by the reference
    float* out = (float*)d_out;
    uint4* Bp  = (uint4*)d_ws;   // NCHUNK*64*16 = 557,056 bytes

    int prep_threads = NCHUNK * 64;
    sindy_prep<<<(prep_threads + 255) / 256, 256, 0, stream>>>(Xi, Xi_mask, Bp);
    sindy_mfma<<<NBLK, 256, 0, stream>>>(z, Xi, Xi_mask, Bp, out);
}

// Round 3
// 140.086 us; speedup vs baseline: 15.9434x; 1.2940x over previous
//
#include <hip/hip_runtime.h>

// SINDy: out[65536,32] = Theta(z)[65536,6545] @ (Xi*Xi_mask)[6545,32]
// Round-3: round-2 structure (augmented z~=(z,1), term = p(i,j) * z~[8q+jj],
// 4 static-q segments, B pre-packed to fragment order in ws) plus:
//  - 4-deep register double-buffered prefetch of the B stream (latency fix)
//  - pre-scaled meta tables (byte offsets) + v_cvt_pk_bf16_f32 pack (VALU trim)
//  - segments padded to multiples of 4 chunks (544 -> 552, pads contribute 0)
// MFMA 32x32x16_bf16 layouts (verified rounds 1-2):
//   A[m][k]: m=lane&31, k=(lane>>5)*8+jj
//   B[k][n]: n=lane&31, k=(lane>>5)*8+jj
//   C/D:     col=lane&31, row=(reg&3)+8*(reg>>2)+4*(lane>>5)

#define Z 32
#define ROWS 65536
#define WPB 4
#define NBLK (ROWS / 32 / WPB)   // 512 blocks x 4 waves, one 32x32 tile per wave

#define NCHUNK 552               // 36 + 84 + 160 + 272 (each %4 == 0)
#define NGRAN (NCHUNK * 2)

typedef short short8 __attribute__((ext_vector_type(8)));
typedef float f32x16 __attribute__((ext_vector_type(16)));

struct Sched {
    int nq[4];                 // chunks per quarter-segment (each %4==0)
    unsigned mlo[NCHUNK];      // granule 0: (i*4) | (j*4)<<16   (byte offsets into z-row)
    unsigned mhi[NCHUNK];      // granule 1: same
    short gi[NGRAN], gj[NGRAN];
    char gtype[NGRAN];         // 0 triple, 1 pair, 2 linear, 3 pad
    char gq[NGRAN];            // quarter of granule
    int tidx[32][32];          // triple-block index of (a,b,b)
    int pidx[32];              // pair-block index of (i,i)
};

constexpr Sched make_sched() {
    Sched s{};
    int g = 0;
    for (int q = 0; q < 4; ++q) {
        int g0 = g;
        // triples (a<=b): granule covers k in [8q,8q+8) for k>=b -> need b>>3 <= q
        for (int b = 0; b < 32; ++b)
            if ((b >> 3) <= q)
                for (int a = 0; a <= b; ++a) {
                    s.gi[g] = (short)a; s.gj[g] = (short)b; s.gtype[g] = 0; s.gq[g] = (char)q; ++g;
                }
        // pairs (b,32): theta = z_b*z_k, valid k<=b -> need b>>3 >= q
        for (int b = 0; b < 32; ++b)
            if ((b >> 3) >= q) {
                s.gi[g] = (short)b; s.gj[g] = 32; s.gtype[g] = 1; s.gq[g] = (char)q; ++g;
            }
        // linear: theta = z_k
        s.gi[g] = 32; s.gj[g] = 32; s.gtype[g] = 2; s.gq[g] = (char)q; ++g;
        // pad granules until quarter has a multiple of 8 granules (4 chunks)
        while ((g - g0) & 7) { s.gi[g] = 32; s.gj[g] = 32; s.gtype[g] = 3; s.gq[g] = (char)q; ++g; }
        s.nq[q] = (g - g0) / 2;
    }
    for (int c = 0; c < NCHUNK; ++c) {
        s.mlo[c] = ((unsigned)s.gi[2*c]   * 4u) | (((unsigned)s.gj[2*c]   * 4u) << 16);
        s.mhi[c] = ((unsigned)s.gi[2*c+1] * 4u) | (((unsigned)s.gj[2*c+1] * 4u) << 16);
    }
    int n = 0;
    for (int a = 0; a < 32; ++a)
        for (int b = a; b < 32; ++b) { s.tidx[a][b] = n; n += 32 - b; }
    for (int i = 0; i < 32; ++i) s.pidx[i] = i * 32 - i * (i - 1) / 2;
    return s;
}
constexpr Sched S = make_sched();
static_assert(S.nq[0] == 36 && S.nq[1] == 84 && S.nq[2] == 160 && S.nq[3] == 272, "chunk counts");
static_assert(S.tidx[31][31] == 5983, "triple indexing");

__device__ __forceinline__ unsigned pack_bf16(float s0, float s1) {
#if __has_builtin(__builtin_amdgcn_cvt_pk_bf16_f32)
    return __builtin_bit_cast(unsigned, __builtin_amdgcn_cvt_pk_bf16_f32(s0, s1));
#else
    unsigned b0 = __builtin_bit_cast(unsigned, s0) + 0x8000u;
    unsigned b1 = __builtin_bit_cast(unsigned, s1) + 0x8000u;
    return __builtin_amdgcn_perm(b1, b0, 0x07060302u);   // lo16=s0, hi16=s1
#endif
}

// ---- prep: pack Xi_eff (bf16 RNE) into granule-ordered B fragments in ws ----
__global__ void sindy_prep(const float* __restrict__ Xi,
                           const float* __restrict__ Xi_mask,
                           uint4* __restrict__ Bp, size_t ws_size) {
    int tid = blockIdx.x * blockDim.x + threadIdx.x;
    if (tid >= NCHUNK * 64) return;
    if ((size_t)(tid + 1) * 16 > ws_size) return;   // safety; unwritten pads ~ +-3e-13
    int c = tid >> 6, l = tid & 63;
    int g = 2 * c + (l >> 5);
    int n = l & 31;
    int i = S.gi[g], j = S.gj[g], ty = S.gtype[g], q = S.gq[g];
    unsigned v[8];
#pragma unroll
    for (int jj = 0; jj < 8; ++jj) {
        int k = 8 * q + jj;
        int row = -1;
        if (ty == 0)      { if (k >= j) row = 561 + S.tidx[i][j] + (k - j); }   // triple (i,j,k)
        else if (ty == 1) { if (k <= i) row = 33 + S.pidx[k] + (i - k); }       // pair (k,i)
        else if (ty == 2) { row = 1 + k; }                                      // linear z_k
        float f = 0.0f;
        if (row >= 0) f = Xi[row * Z + n] * Xi_mask[row * Z + n];
        unsigned u = __builtin_bit_cast(unsigned, f);
        v[jj] = (u + 0x7FFFu + ((u >> 16) & 1u)) >> 16;   // RNE to bf16
    }
    uint4 o;
    o.x = v[0] | (v[1] << 16);
    o.y = v[2] | (v[3] << 16);
    o.z = v[4] | (v[5] << 16);
    o.w = v[6] | (v[7] << 16);
    Bp[tid] = o;
}

// ---- segment runner: 4-chunk groups, register double-buffered B prefetch ----
template<int Q>
__device__ __forceinline__ void seg_run(int c0, int nG,
                                        const uint4* __restrict__ bpl,  // Bp + lane
                                        const float (&zr)[32],
                                        const char* zbase, bool hi, f32x16& acc) {
    const uint4* p = bpl + (size_t)c0 * 64;
    uint4 cur0 = p[0], cur1 = p[64], cur2 = p[128], cur3 = p[192];
    int c = c0;
    auto body = [&](uint4 b0, uint4 b1, uint4 b2, uint4 b3) {
        const uint4 bb[4] = {b0, b1, b2, b3};
#pragma unroll
        for (int i = 0; i < 4; ++i) {
            unsigned lo = S.mlo[c + i], hh = S.mhi[c + i];   // uniform -> s_load
            unsigned mw = hi ? hh : lo;
            float zi = *(const float*)(zbase + (mw & 0xFFFFu));
            float zj = *(const float*)(zbase + (mw >> 16));
            float pp = zi * zj;
            union { unsigned u[4]; short8 s; } a;
#pragma unroll
            for (int r = 0; r < 4; ++r)
                a.u[r] = pack_bf16(pp * zr[8 * Q + 2 * r], pp * zr[8 * Q + 2 * r + 1]);
            union { uint4 v; short8 s; } b; b.v = bb[i];
            acc = __builtin_amdgcn_mfma_f32_32x32x16_bf16(a.s, b.s, acc, 0, 0, 0);
        }
        c += 4;
    };
    for (int g = 0; g < nG - 1; ++g) {
        const uint4* pn = p + 256;
        uint4 n0 = pn[0], n1 = pn[64], n2 = pn[128], n3 = pn[192];
        body(cur0, cur1, cur2, cur3);
        cur0 = n0; cur1 = n1; cur2 = n2; cur3 = n3;
        p = pn;
    }
    body(cur0, cur1, cur2, cur3);
}

// ---- main: one wave per 32x32 output tile ----
__global__ __launch_bounds__(256, 2) void sindy_mfma(const float* __restrict__ z,
                                                     const float* __restrict__ Xi,
                                                     const float* __restrict__ Xi_mask,
                                                     const uint4* __restrict__ Bp,
                                                     float* __restrict__ out) {
    const int lane = threadIdx.x & 63;
    const int w = threadIdx.x >> 6;
    const int m = lane & 31;
    const int half = lane >> 5;
    const int wave = blockIdx.x * WPB + w;
    const long R = (long)wave * 32;

    __shared__ float zs[WPB][32][33];   // stride 33 -> p-reads conflict-free

    float zr[32];
    const float4* z4 = (const float4*)(z + (R + m) * Z);
#pragma unroll
    for (int t = 0; t < 8; ++t) {
        float4 v = z4[t];
        zr[4*t+0] = v.x; zr[4*t+1] = v.y; zr[4*t+2] = v.z; zr[4*t+3] = v.w;
    }
#pragma unroll
    for (int t = 0; t < 16; ++t) zs[w][m][half * 16 + t] = zr[half * 16 + t];
    if (half == 0) zs[w][m][32] = 1.0f;   // z~[32] = 1.0 sentinel
    __syncthreads();

    const float bias = Xi[m] * Xi_mask[m];   // library row 0 (ones), col n = m
    f32x16 acc = {};
    const char* zbase = (const char*)&zs[w][m][0];
    const uint4* bpl = Bp + lane;
    const bool hi = (half != 0);

    seg_run<0>(  0,  9, bpl, zr, zbase, hi, acc);
    seg_run<1>( 36, 21, bpl, zr, zbase, hi, acc);
    seg_run<2>(120, 40, bpl, zr, zbase, hi, acc);
    seg_run<3>(280, 68, bpl, zr, zbase, hi, acc);

#pragma unroll
    for (int r = 0; r < 16; ++r) acc[r] += bias;

    float* orow = out + R * Z;
#pragma unroll
    for (int r = 0; r < 16; ++r) {
        int row = (r & 3) + 8 * (r >> 2) + 4 * half;
        orow[row * Z + m] = acc[r];
    }
}

extern "C" void kernel_launch(void* const* d_in, const int* in_sizes, int n_in,
                              void* d_out, int out_size, void* d_ws, size_t ws_size,
                              hipStream_t stream) {
    const float* z       = (const float*)d_in[0];
    const float* Xi      = (const float*)d_in[1];
    const float* Xi_mask = (const float*)d_in[2];
    // d_in[3]=z_mean, d_in[4]=z_std: unused by the reference
    float* out = (float*)d_out;
    uint4* Bp  = (uint4*)d_ws;   // NCHUNK*64*16 = 565,248 bytes

    int prep_threads = NCHUNK * 64;
    sindy_prep<<<(prep_threads + 255) / 256, 256, 0, stream>>>(Xi, Xi_mask, Bp, ws_size);
    sindy_mfma<<<NBLK, 256, 0, stream>>>(z, Xi, Xi_mask, Bp, out);
}